// Round 19
// baseline (67.119 us; speedup 1.0000x reference)
//
#include <hip/hip_runtime.h>
#include <hip/hip_bf16.h>

using short8 = __attribute__((ext_vector_type(8))) short;
using f32x4  = __attribute__((ext_vector_type(4))) float;

#define HD 128
#define NN 256
#define NB 2048

static __device__ __forceinline__ unsigned short us(float v) {
    union { __hip_bfloat16 b; unsigned short s; } c; c.b = __float2bfloat16(v); return c.s;
}
static __device__ __forceinline__ unsigned int pk2(float a, float b) {
    return (unsigned int)us(a) | ((unsigned int)us(b) << 16);
}
static __device__ __forceinline__ float fsilu(float v) {
    return __fdividef(v, 1.f + __expf(-v));
}
static __device__ __forceinline__ float ftanh(float v) {
    return 1.f - __fdividef(2.f, __expf(2.f * v) + 1.f);
}
// XOR-swizzled LDS byte addr for [rows][128] bf16 tile (256B row stride)
static __device__ __forceinline__ int swz(int row, int kbyte) { return row * 256 + (kbyte ^ ((row & 7) << 4)); }
// XOR-swizzled LDS byte addr for [rows][256] bf16 tile (512B row stride)
static __device__ __forceinline__ int swz512(int row, int kbyte) { return row * 512 + (kbyte ^ ((row & 7) << 4)); }

// ---- fused prep: weight packing + mask compaction + Apre/Bpre node GEMM ----
// blocks [0,320): pack we2/wc1/wn1/wn2 -> bf16 fragment layout
// blocks [320,328): per-batch mask compaction (full permutation)
// blocks [328,456): Apre/Bpre = h @ [we1_lo | we1_hi] via MFMA, B-frags gathered
//                   from RAW fp32 we1 (no packed we1 needed -> no dependency)
__global__ __launch_bounds__(256) void prep_fused(
    const float* __restrict__ we2, const float* __restrict__ wc1,
    const float* __restrict__ wn1, const float* __restrict__ wn2,
    const float* __restrict__ we1, const int* __restrict__ mask,
    const float* __restrict__ h, const float* __restrict__ be1,
    unsigned short* __restrict__ we2pk, unsigned short* __restrict__ wc1pk,
    unsigned short* __restrict__ wn1pk, unsigned short* __restrict__ wn2pk,
    int* __restrict__ idxB, int* __restrict__ cntB,
    float* __restrict__ Apre, float* __restrict__ Bpre)
{
    const int blk = blockIdx.x;
    const int tid = threadIdx.x;
    if (blk < 320) {
        const int idx = blk * 256 + tid;        // 0..81919
        const float* src; unsigned short* dst; int local;
        if (idx < 16384)      { src = we2; dst = we2pk; local = idx;         }
        else if (idx < 32768) { src = wc1; dst = wc1pk; local = idx - 16384; }
        else if (idx < 65536) { src = wn1; dst = wn1pk; local = idx - 32768; }
        else                  { src = wn2; dst = wn2pk; local = idx - 65536; }
        const int k = local >> 7, n = local & 127;
        dst[((k >> 3) * 128 + n) * 8 + (k & 7)] = us(src[local]);
    } else if (blk < 328) {
        // mask compaction: actives at [0,cnt), inactives at [cnt,256)
        const int b = blk - 320;                // 0..7
        const int lane = tid & 63, wvp = tid >> 6;
        const int m = mask[b * NN + tid];
        const unsigned long long bal = __ballot(m != 0);
        const int pos = __popcll(bal & ((1ULL << lane) - 1ULL));
        __shared__ int wc[4];
        if (lane == 0) wc[wvp] = __popcll(bal);
        __syncthreads();
        int base = 0;
        for (int w = 0; w < wvp; ++w) base += wc[w];
        const int cnt = wc[0] + wc[1] + wc[2] + wc[3];
        const int act_before = base + pos;
        const int slot = m ? act_before : cnt + (tid - act_before);
        idxB[b * NN + slot] = tid;
        if (tid == 0) cntB[b] = cnt;
    } else {
        // node GEMM: 16 rows per block
        const int r0 = (blk - 328) * 16;
        const int wv = tid >> 6, lane = tid & 63, g = lane >> 4, cl = lane & 15;
        __shared__ __align__(16) unsigned short t1[16 * HD];
        {
            const int row = tid >> 4, k0 = (tid & 15) * 8;
            const float4 a0 = *(const float4*)(h + (size_t)(r0 + row) * HD + k0);
            const float4 a1 = *(const float4*)(h + (size_t)(r0 + row) * HD + k0 + 4);
            uint4 o;
            o.x = pk2(a0.x, a0.y); o.y = pk2(a0.z, a0.w);
            o.z = pk2(a1.x, a1.y); o.w = pk2(a1.z, a1.w);
            *(uint4*)((char*)t1 + swz(row, 2 * k0)) = o;
        }
        __syncthreads();
        const f32x4 zero4 = {0.f, 0.f, 0.f, 0.f};
        f32x4 acc[4] = {zero4, zero4, zero4, zero4};
        #pragma unroll
        for (int ks = 0; ks < 4; ++ks) {
            const short8 a = *(const short8*)((char*)t1 + swz(cl, ks * 64 + g * 16));
            const int k0 = ks * 32 + g * 8;
            #pragma unroll
            for (int nt = 0; nt < 4; ++nt) {
                const int col = wv * 64 + nt * 16 + cl;
                // W[k][col] = (col<128) ? we1[k][col] : we1[128+k][col-128]
                const float* wsrc = (col < HD) ? (we1 + (size_t)k0 * HD + col)
                                               : (we1 + (size_t)(HD + k0) * HD + (col - HD));
                uint4 wp;
                wp.x = pk2(wsrc[0 * HD], wsrc[1 * HD]);
                wp.y = pk2(wsrc[2 * HD], wsrc[3 * HD]);
                wp.z = pk2(wsrc[4 * HD], wsrc[5 * HD]);
                wp.w = pk2(wsrc[6 * HD], wsrc[7 * HD]);
                const short8 bb = *(const short8*)&wp;
                acc[nt] = __builtin_amdgcn_mfma_f32_16x16x32_bf16(a, bb, acc[nt], 0, 0, 0);
            }
        }
        #pragma unroll
        for (int nt = 0; nt < 4; ++nt) {
            const int col = wv * 64 + nt * 16 + cl;
            const float bias = (col < HD) ? be1[col] : 0.f;
            #pragma unroll
            for (int r = 0; r < 4; ++r) {
                const int row = r0 + g * 4 + r;
                const float v = acc[nt][r] + bias;
                if (col < HD) Apre[(size_t)row * HD + col] = v;
                else          Bpre[(size_t)row * HD + (col - HD)] = v;
            }
        }
    }
}

// ---- main: 2 blocks (256 thr / 4 waves each) per node; block owns a j-half ----
// Operand-SWAPPED MFMA: D = W^T x M^T -> lane index = j-row, regs = output cols.
// One barrier per chunk, (256,3): no spill. [R16 compute structure — best]
// Inactive blocks exit without writes (aggp/cdws pre-zeroed via memset).
__global__ __launch_bounds__(256, 3) void egcl_main(
    const float* __restrict__ x, const float* __restrict__ we1,
    const float* __restrict__ be2, const float* __restrict__ bc1,
    const float* __restrict__ wc2,
    const float* __restrict__ Apre, const float* __restrict__ Bpre,
    const unsigned short* __restrict__ we2pk, const unsigned short* __restrict__ wc1pk,
    const int* __restrict__ idxB, const int* __restrict__ cntB,
    float* __restrict__ aggp, float4* __restrict__ cdws)
{
    const int blk = blockIdx.x;              // 0..4095
    const int b = blk >> 9;
    const int q = blk & 511;
    const int p = q >> 1, hh = q & 1;
    const int tid = threadIdx.x;
    const int wv = tid >> 6, lane = tid & 63, g = lane >> 4, cl = lane & 15;

    const int cnt = cntB[b];
    const int i = idxB[b * NN + p];          // full permutation: [actives | inactives]
    const int rowb = b * NN + i;

    const int nch_t = (cnt + 15) >> 4;
    const int c0 = ((nch_t + 1) >> 1) << 4;  // rows for half 0 (multiple of 16)
    const int jbase = hh ? c0 : 0;
    const int jend  = hh ? cnt : (c0 < cnt ? c0 : cnt);
    const int hcnt  = jend - jbase;

    if (p >= cnt || hcnt <= 0) return;       // partials pre-zeroed by memset

    __shared__ __align__(16) unsigned short m1buf[2][16 * HD]; // 8KB double buffer
    __shared__ __align__(16) unsigned short t2buf[2][16 * HD]; // 8KB double buffer
    __shared__ __align__(16) float4 jx_s[128];                 // {d2, xj0, xj1, xj2} 2KB
    __shared__ int j_s[128];                                   // 512B
    __shared__ __align__(16) float Ai_s[HD], wl_s[HD];         // 1KB
    __shared__ float swsbuf[8][4][16];                         // per-chunk partials 2KB
    __shared__ float cdp[4][3];

    const float xi0 = x[rowb * 3 + 0];
    const float xi1 = x[rowb * 3 + 1];
    const float xi2 = x[rowb * 3 + 2];
    const int nch = (hcnt + 15) >> 4;        // <= 8

    // block-start staging: local j list, xj, d2; Ai; wlast
    if (tid < nch * 16) {
        const int j = (tid < hcnt) ? idxB[b * NN + jbase + tid] : i;
        const float* xj = x + (b * NN + j) * 3;
        const float x0 = xj[0], x1 = xj[1], x2 = xj[2];
        const float dx = xi0 - x0, dy = xi1 - x1, dz = xi2 - x2;
        float4 v; v.x = dx * dx + dy * dy + dz * dz + 1e-8f;
        v.y = x0; v.z = x1; v.w = x2;
        jx_s[tid] = v; j_s[tid] = j;
    }
    if (tid < HD) Ai_s[tid] = Apre[(size_t)rowb * HD + tid];
    else if (tid < 2 * HD) wl_s[tid - HD] = we1[2 * HD * HD + (tid - HD)];

    // per-wave weight fragments: wave owns output cols [wv*32, wv*32+32)
    short8 bw2[4][2], bwc[4][2];
    #pragma unroll
    for (int ks = 0; ks < 4; ++ks) {
        #pragma unroll
        for (int nt = 0; nt < 2; ++nt) {
            const int off = ((ks * 4 + g) * HD + wv * 32 + nt * 16 + cl) * 8;
            bw2[ks][nt] = *(const short8*)(we2pk + off);
            bwc[ks][nt] = *(const short8*)(wc1pk + off);
        }
    }
    // per-(nt,ri) bias/scale scalars at n = wv*32 + nt*16 + g*4 + ri
    float be2v[2][4], bc1v[2][4], wc2v[2][4];
    #pragma unroll
    for (int nt = 0; nt < 2; ++nt) {
        #pragma unroll
        for (int ri = 0; ri < 4; ++ri) {
            const int n = wv * 32 + nt * 16 + g * 4 + ri;
            be2v[nt][ri] = be2[n]; bc1v[nt][ri] = bc1[n]; wc2v[nt][ri] = wc2[n];
        }
    }

    float agg2[2][4] = {{0.f, 0.f, 0.f, 0.f}, {0.f, 0.f, 0.f, 0.f}};
    const f32x4 zero4 = {0.f, 0.f, 0.f, 0.f};

    // phase-A lane mapping: 256 lanes cover [16 rows][128 K], 8 K-elems each
    const int arow = tid >> 4;           // 0..15
    const int ak0  = (tid & 15) * 8;     // 0,8,...,120
    float4 sb0, sb1;                     // prefetched Bpre[j, ak0..ak0+8)

    // issue Bpre loads for chunk C (held in regs across GEMM1/epi1)
    #define ISSUE(C) do { \
        const float* bp_ = Bpre + (size_t)(b * NN + j_s[(C) * 16 + arow]) * HD + ak0; \
        sb0 = *(const float4*)(bp_); \
        sb1 = *(const float4*)(bp_ + 4); \
    } while (0)

    // phase A for chunk C -> dst buffer (consumes sb0/sb1)
    #define APHASE(C, DST) do { \
        const float d2_ = jx_s[(C) * 16 + arow].x; \
        const float4 a0 = *(const float4*)(Ai_s + ak0); \
        const float4 a1 = *(const float4*)(Ai_s + ak0 + 4); \
        const float4 w0 = *(const float4*)(wl_s + ak0); \
        const float4 w1 = *(const float4*)(wl_s + ak0 + 4); \
        uint4 o; \
        o.x = pk2(fsilu(a0.x + sb0.x + d2_ * w0.x), fsilu(a0.y + sb0.y + d2_ * w0.y)); \
        o.y = pk2(fsilu(a0.z + sb0.z + d2_ * w0.z), fsilu(a0.w + sb0.w + d2_ * w0.w)); \
        o.z = pk2(fsilu(a1.x + sb1.x + d2_ * w1.x), fsilu(a1.y + sb1.y + d2_ * w1.y)); \
        o.w = pk2(fsilu(a1.z + sb1.z + d2_ * w1.z), fsilu(a1.w + sb1.w + d2_ * w1.w)); \
        *(uint4*)((char*)(DST) + swz(arow, 2 * ak0)) = o; \
    } while (0)

    unsigned short* m1cur = m1buf[0];
    unsigned short* m1nxt = m1buf[1];
    unsigned short* t2cur = t2buf[0];
    unsigned short* t2nxt = t2buf[1];

    __syncthreads();                 // staging LDS visible
    ISSUE(0);
    APHASE(0, m1cur);
    __syncthreads();                 // m1cur visible

    for (int c = 0; c < nch; ++c) {
        // issue next chunk's loads early: GEMM1+epi1 cover the L2 latency
        if (c + 1 < nch) ISSUE(c + 1);
        // ---- GEMM1 (swapped): acc[nt] = out1^T tiles; lane col = j-row ----
        f32x4 acc[2] = {zero4, zero4};
        #pragma unroll
        for (int ks = 0; ks < 4; ++ks) {
            const short8 mf = *(const short8*)((const char*)m1cur + swz(cl, 2 * (ks * 32 + g * 8)));
            acc[0] = __builtin_amdgcn_mfma_f32_16x16x32_bf16(bw2[ks][0], mf, acc[0], 0, 0, 0);
            acc[1] = __builtin_amdgcn_mfma_f32_16x16x32_bf16(bw2[ks][1], mf, acc[1], 0, 0, 0);
        }
        // ---- epilogue 1: v = silu(+be2)*mask(row=cl); agg; 2x b64 store ----
        {
            const float mp = (c * 16 + cl < hcnt) ? 1.f : 0.f;
            #pragma unroll
            for (int nt = 0; nt < 2; ++nt) {
                const float v0 = fsilu(acc[nt][0] + be2v[nt][0]) * mp;
                const float v1 = fsilu(acc[nt][1] + be2v[nt][1]) * mp;
                const float v2 = fsilu(acc[nt][2] + be2v[nt][2]) * mp;
                const float v3 = fsilu(acc[nt][3] + be2v[nt][3]) * mp;
                agg2[nt][0] += v0; agg2[nt][1] += v1;
                agg2[nt][2] += v2; agg2[nt][3] += v3;
                uint2 o; o.x = pk2(v0, v1); o.y = pk2(v2, v3);
                *(uint2*)((char*)t2cur + swz(cl, 2 * (wv * 32 + nt * 16 + g * 4))) = o;
            }
        }
        // ---- next chunk's phase A into the other m1 buffer ----
        if (c + 1 < nch) APHASE(c + 1, m1nxt);
        __syncthreads();             // the ONLY barrier per chunk
        // ---- GEMM2 (swapped): acc2[nt] = out2^T tiles ----
        f32x4 acc2[2] = {zero4, zero4};
        #pragma unroll
        for (int ks = 0; ks < 4; ++ks) {
            const short8 tf = *(const short8*)((const char*)t2cur + swz(cl, 2 * (ks * 32 + g * 8)));
            acc2[0] = __builtin_amdgcn_mfma_f32_16x16x32_bf16(bwc[ks][0], tf, acc2[0], 0, 0, 0);
            acc2[1] = __builtin_amdgcn_mfma_f32_16x16x32_bf16(bwc[ks][1], tf, acc2[1], 0, 0, 0);
        }
        // ---- epilogue 2: in-lane col reduction; 2 shfl across g; -> swsbuf[c] ----
        {
            float sr = fsilu(acc2[0][0] + bc1v[0][0]) * wc2v[0][0]
                     + fsilu(acc2[0][1] + bc1v[0][1]) * wc2v[0][1]
                     + fsilu(acc2[0][2] + bc1v[0][2]) * wc2v[0][2]
                     + fsilu(acc2[0][3] + bc1v[0][3]) * wc2v[0][3]
                     + fsilu(acc2[1][0] + bc1v[1][0]) * wc2v[1][0]
                     + fsilu(acc2[1][1] + bc1v[1][1]) * wc2v[1][1]
                     + fsilu(acc2[1][2] + bc1v[1][2]) * wc2v[1][2]
                     + fsilu(acc2[1][3] + bc1v[1][3]) * wc2v[1][3];
            sr += __shfl_xor(sr, 16);
            sr += __shfl_xor(sr, 32);
            if (lane < 16) swsbuf[c][wv][cl] = sr;
        }
        // swap buffers
        unsigned short* tmp = m1cur; m1cur = m1nxt; m1nxt = tmp;
        tmp = t2cur; t2cur = t2nxt; t2nxt = tmp;
    }
    #undef ISSUE
    #undef APHASE
    __syncthreads();                 // all swsbuf visible

    // ---- deferred coord finalize: thread jl handles one j ----
    float cdx = 0.f, cdy = 0.f, cdz = 0.f;
    if (tid < hcnt) {
        const int ch = tid >> 4, row = tid & 15;
        const float s = swsbuf[ch][0][row] + swsbuf[ch][1][row]
                      + swsbuf[ch][2][row] + swsbuf[ch][3][row];
        const float w = ftanh(s) * 0.1f;
        const float4 jx = jx_s[tid];
        cdx = (xi0 - jx.y) * w;
        cdy = (xi1 - jx.z) * w;
        cdz = (xi2 - jx.w) * w;
    }
    #pragma unroll
    for (int m = 1; m <= 32; m <<= 1) {
        cdx += __shfl_xor(cdx, m);
        cdy += __shfl_xor(cdy, m);
        cdz += __shfl_xor(cdz, m);
    }
    if (lane == 0) { cdp[wv][0] = cdx; cdp[wv][1] = cdy; cdp[wv][2] = cdz; }

    // agg: reduce each (nt,ri) over j-rows (cl lanes); lane cl==0 per g writes
    const size_t aggbase = ((size_t)hh * NB + rowb) * HD;
    #pragma unroll
    for (int nt = 0; nt < 2; ++nt) {
        #pragma unroll
        for (int ri = 0; ri < 4; ++ri) {
            float a = agg2[nt][ri];
            a += __shfl_xor(a, 1); a += __shfl_xor(a, 2);
            a += __shfl_xor(a, 4); a += __shfl_xor(a, 8);
            if (cl == 0) aggp[aggbase + wv * 32 + nt * 16 + g * 4 + ri] = a;
        }
    }
    __syncthreads();
    if (tid == 0) {
        cdws[hh * NB + rowb] = make_float4(cdp[0][0] + cdp[1][0] + cdp[2][0] + cdp[3][0],
                                           cdp[0][1] + cdp[1][1] + cdp[2][1] + cdp[3][1],
                                           cdp[0][2] + cdp[1][2] + cdp[2][2] + cdp[3][2], 0.f);
    }
}

// ---- node MLP + LayerNorm + coord finalize: 16 rows per block ----
__global__ __launch_bounds__(256) void node_mlp(
    const float* __restrict__ h, const float* __restrict__ x,
    const float* __restrict__ aggp, const float4* __restrict__ cdws,
    const unsigned short* __restrict__ wn1pk, const unsigned short* __restrict__ wn2pk,
    const float* __restrict__ bn1, const float* __restrict__ bn2,
    const float* __restrict__ gamma, const float* __restrict__ beta,
    float* __restrict__ hout, float* __restrict__ xout)
{
    const int r0 = blockIdx.x * 16;
    const int tid = threadIdx.x;
    const int wv = tid >> 6, lane = tid & 63, g = lane >> 4, cl = lane & 15;
    __shared__ __align__(16) unsigned short t1[16 * 256];
    __shared__ __align__(16) unsigned short t2[16 * HD];
    __shared__ float rs1[4][16], rs2[4][16];
    __shared__ float bn1_s[HD], bn2_s[HD], gam_s[HD], bet_s[HD];
    if (tid < HD) {
        bn1_s[tid] = bn1[tid]; bn2_s[tid] = bn2[tid];
        gam_s[tid] = gamma[tid]; bet_s[tid] = beta[tid];
    }
    // coord finalize (independent of the MLP)
    if (tid >= 128 && tid < 144) {
        const int row = r0 + (tid - 128);
        const float4 c0 = cdws[row], c1 = cdws[NB + row];
        xout[row * 3 + 0] = x[row * 3 + 0] + (c0.x + c1.x) * (1.f / 256.f);
        xout[row * 3 + 1] = x[row * 3 + 1] + (c0.y + c1.y) * (1.f / 256.f);
        xout[row * 3 + 2] = x[row * 3 + 2] + (c0.z + c1.z) * (1.f / 256.f);
    }
    // stage A tile: [16 rows][256 k] = [h | agg0+agg1] bf16, swizzled
    {
        const int row = tid >> 4, k0 = (tid & 15) * 16;
        const size_t off = (size_t)(r0 + row) * HD;
        char* dst = (char*)t1;
        if (k0 < HD) {
            #pragma unroll
            for (int u = 0; u < 16; u += 8) {
                const float4 a0 = *(const float4*)(h + off + k0 + u);
                const float4 a1 = *(const float4*)(h + off + k0 + u + 4);
                uint4 o;
                o.x = pk2(a0.x, a0.y); o.y = pk2(a0.z, a0.w);
                o.z = pk2(a1.x, a1.y); o.w = pk2(a1.z, a1.w);
                *(uint4*)(dst + swz512(row, 2 * (k0 + u))) = o;
            }
        } else {
            const int kk = k0 - HD;
            #pragma unroll
            for (int u = 0; u < 16; u += 8) {
                const float4 a0 = *(const float4*)(aggp + off + kk + u);
                const float4 a1 = *(const float4*)(aggp + off + kk + u + 4);
                const float4 b0 = *(const float4*)(aggp + (size_t)NB * HD + off + kk + u);
                const float4 b1 = *(const float4*)(aggp + (size_t)NB * HD + off + kk + u + 4);
                uint4 o;
                o.x = pk2(a0.x + b0.x, a0.y + b0.y); o.y = pk2(a0.z + b0.z, a0.w + b0.w);
                o.z = pk2(a1.x + b1.x, a1.y + b1.y); o.w = pk2(a1.z + b1.z, a1.w + b1.w);
                *(uint4*)(dst + swz512(row, 2 * (k0 + u))) = o;
            }
        }
    }
    __syncthreads();
    const f32x4 zero4 = {0.f, 0.f, 0.f, 0.f};
    f32x4 acc[2] = {zero4, zero4};
    #pragma unroll
    for (int ks = 0; ks < 8; ++ks) {
        const short8 a = *(const short8*)((char*)t1 + swz512(cl, ks * 64 + g * 16));
        #pragma unroll
        for (int nt = 0; nt < 2; ++nt) {
            const int col = wv * 32 + nt * 16 + cl;
            const short8 bb = *(const short8*)(wn1pk + ((ks * 4 + g) * HD + col) * 8);
            acc[nt] = __builtin_amdgcn_mfma_f32_16x16x32_bf16(a, bb, acc[nt], 0, 0, 0);
        }
    }
    #pragma unroll
    for (int nt = 0; nt < 2; ++nt) {
        const int col = wv * 32 + nt * 16 + cl;
        const float bias = bn1_s[col];
        #pragma unroll
        for (int r = 0; r < 4; ++r) {
            const int row = g * 4 + r;
            *(unsigned short*)((char*)t2 + swz(row, 2 * col)) = us(fsilu(acc[nt][r] + bias));
        }
    }
    __syncthreads();
    f32x4 acc2[2] = {zero4, zero4};
    #pragma unroll
    for (int ks = 0; ks < 4; ++ks) {
        const short8 a = *(const short8*)((char*)t2 + swz(cl, ks * 64 + g * 16));
        #pragma unroll
        for (int nt = 0; nt < 2; ++nt) {
            const int col = wv * 32 + nt * 16 + cl;
            const short8 bb = *(const short8*)(wn2pk + ((ks * 4 + g) * HD + col) * 8);
            acc2[nt] = __builtin_amdgcn_mfma_f32_16x16x32_bf16(a, bb, acc2[nt], 0, 0, 0);
        }
    }
    float h2[2][4];
    #pragma unroll
    for (int nt = 0; nt < 2; ++nt) {
        const int col = wv * 32 + nt * 16 + cl;
        #pragma unroll
        for (int r = 0; r < 4; ++r) {
            const int row = g * 4 + r;
            h2[nt][r] = acc2[nt][r] + bn2_s[col] + h[(size_t)(r0 + row) * HD + col];
        }
    }
    #pragma unroll
    for (int r = 0; r < 4; ++r) {
        float pp = h2[0][r] + h2[1][r];
        pp += __shfl_xor(pp, 1); pp += __shfl_xor(pp, 2);
        pp += __shfl_xor(pp, 4); pp += __shfl_xor(pp, 8);
        if (cl == 0) rs1[wv][g * 4 + r] = pp;
    }
    __syncthreads();
    float mean[4];
    #pragma unroll
    for (int r = 0; r < 4; ++r) {
        const int row = g * 4 + r;
        mean[r] = (rs1[0][row] + rs1[1][row] + rs1[2][row] + rs1[3][row]) * (1.f / HD);
    }
    #pragma unroll
    for (int r = 0; r < 4; ++r) {
        const float d0 = h2[0][r] - mean[r], d1 = h2[1][r] - mean[r];
        float qq = d0 * d0 + d1 * d1;
        qq += __shfl_xor(qq, 1); qq += __shfl_xor(qq, 2);
        qq += __shfl_xor(qq, 4); qq += __shfl_xor(qq, 8);
        if (cl == 0) rs2[wv][g * 4 + r] = qq;
    }
    __syncthreads();
    #pragma unroll
    for (int r = 0; r < 4; ++r) {
        const int row = g * 4 + r;
        const float var = (rs2[0][row] + rs2[1][row] + rs2[2][row] + rs2[3][row]) * (1.f / HD);
        const float rsq = rsqrtf(var + 1e-5f);
        #pragma unroll
        for (int nt = 0; nt < 2; ++nt) {
            const int col = wv * 32 + nt * 16 + cl;
            hout[(size_t)(r0 + row) * HD + col] = (h2[nt][r] - mean[r]) * rsq * gam_s[col] + bet_s[col];
        }
    }
}

extern "C" void kernel_launch(void* const* d_in, const int* in_sizes, int n_in,
                              void* d_out, int out_size, void* d_ws, size_t ws_size,
                              hipStream_t stream)
{
    (void)in_sizes; (void)n_in; (void)out_size; (void)ws_size;
    const float* h     = (const float*)d_in[0];
    const float* x     = (const float*)d_in[1];
    const int*   mask  = (const int*)d_in[2];
    const float* we1   = (const float*)d_in[3];
    const float* be1   = (const float*)d_in[4];
    const float* we2   = (const float*)d_in[5];
    const float* be2   = (const float*)d_in[6];
    const float* wn1   = (const float*)d_in[7];
    const float* bn1   = (const float*)d_in[8];
    const float* wn2   = (const float*)d_in[9];
    const float* bn2   = (const float*)d_in[10];
    const float* wc1   = (const float*)d_in[11];
    const float* bc1   = (const float*)d_in[12];
    const float* wc2   = (const float*)d_in[13];
    const float* gamma = (const float*)d_in[14];
    const float* beta  = (const float*)d_in[15];

    float* out  = (float*)d_out;
    float* hout = out;
    float* xout = out + NB * HD;

    float* Apre  = (float*)d_ws;                       // 2048*128
    float* Bpre  = Apre + NB * HD;                     // 2048*128
    float* aggp  = Bpre + NB * HD;                     // 2*2048*128
    float4* cdws = (float4*)(aggp + 2 * NB * HD);      // 2*2048 float4 (contiguous after aggp)
    unsigned short* we2pk = (unsigned short*)(cdws + 2 * NB);
    unsigned short* wc1pk = we2pk + 128 * 128;
    unsigned short* wn1pk = wc1pk + 128 * 128;
    unsigned short* wn2pk = wn1pk + 256 * 128;
    int* idxB = (int*)(wn2pk + 128 * 128);
    int* cntB = idxB + 8 * NN;

    // zero the partial buffers (aggp + cdws contiguous): inactive tasks never write
    hipMemsetAsync(aggp, 0, (size_t)(2 * NB * HD) * sizeof(float) + (size_t)(2 * NB) * sizeof(float4), stream);
    prep_fused<<<456, 256, 0, stream>>>(we2, wc1, wn1, wn2, we1, mask, h, be1,
                                        we2pk, wc1pk, wn1pk, wn2pk, idxB, cntB,
                                        Apre, Bpre);
    egcl_main<<<NB * 2, 256, 0, stream>>>(x, we1, be2, bc1, wc2,
                                          Apre, Bpre, we2pk, wc1pk, idxB, cntB,
                                          aggp, cdws);
    node_mlp<<<128, 256, 0, stream>>>(h, x, aggp, cdws, wn1pk, wn2pk,
                                      bn1, bn2, gamma, beta, hout, xout);
}

// Round 20
// 56.707 us; speedup vs baseline: 1.1836x; 1.1836x over previous
//
#include <hip/hip_runtime.h>
#include <hip/hip_bf16.h>

using short8 = __attribute__((ext_vector_type(8))) short;
using f32x4  = __attribute__((ext_vector_type(4))) float;

#define HD 128
#define NN 256
#define NB 2048

static __device__ __forceinline__ unsigned short us(float v) {
    union { __hip_bfloat16 b; unsigned short s; } c; c.b = __float2bfloat16(v); return c.s;
}
static __device__ __forceinline__ unsigned int pk2(float a, float b) {
    return (unsigned int)us(a) | ((unsigned int)us(b) << 16);
}
#define LOG2E 1.4426950408889634f
// native-instruction silu: v_exp_f32 (2^x) + v_rcp_f32, 5 instrs total
static __device__ __forceinline__ float fsilu(float v) {
    return v * __builtin_amdgcn_rcpf(1.f + __builtin_amdgcn_exp2f(-v * LOG2E));
}
static __device__ __forceinline__ float ftanh(float v) {
    return 1.f - 2.f * __builtin_amdgcn_rcpf(1.f + __builtin_amdgcn_exp2f(2.f * v * LOG2E));
}
// XOR-swizzled LDS byte addr for [rows][128] bf16 tile (256B row stride)
static __device__ __forceinline__ int swz(int row, int kbyte) { return row * 256 + (kbyte ^ ((row & 7) << 4)); }
// XOR-swizzled LDS byte addr for [rows][256] bf16 tile (512B row stride)
static __device__ __forceinline__ int swz512(int row, int kbyte) { return row * 512 + (kbyte ^ ((row & 7) << 4)); }

// ---- fused prep: weight packing + mask compaction + Apre/Bpre node GEMM ----
__global__ __launch_bounds__(256) void prep_fused(
    const float* __restrict__ we2, const float* __restrict__ wc1,
    const float* __restrict__ wn1, const float* __restrict__ wn2,
    const float* __restrict__ we1, const int* __restrict__ mask,
    const float* __restrict__ h, const float* __restrict__ be1,
    unsigned short* __restrict__ we2pk, unsigned short* __restrict__ wc1pk,
    unsigned short* __restrict__ wn1pk, unsigned short* __restrict__ wn2pk,
    int* __restrict__ idxB, int* __restrict__ cntB,
    float* __restrict__ Apre, float* __restrict__ Bpre)
{
    const int blk = blockIdx.x;
    const int tid = threadIdx.x;
    if (blk < 320) {
        const int idx = blk * 256 + tid;        // 0..81919
        const float* src; unsigned short* dst; int local;
        if (idx < 16384)      { src = we2; dst = we2pk; local = idx;         }
        else if (idx < 32768) { src = wc1; dst = wc1pk; local = idx - 16384; }
        else if (idx < 65536) { src = wn1; dst = wn1pk; local = idx - 32768; }
        else                  { src = wn2; dst = wn2pk; local = idx - 65536; }
        const int k = local >> 7, n = local & 127;
        dst[((k >> 3) * 128 + n) * 8 + (k & 7)] = us(src[local]);
    } else if (blk < 328) {
        // mask compaction: actives at [0,cnt), inactives at [cnt,256)
        const int b = blk - 320;                // 0..7
        const int lane = tid & 63, wvp = tid >> 6;
        const int m = mask[b * NN + tid];
        const unsigned long long bal = __ballot(m != 0);
        const int pos = __popcll(bal & ((1ULL << lane) - 1ULL));
        __shared__ int wc[4];
        if (lane == 0) wc[wvp] = __popcll(bal);
        __syncthreads();
        int base = 0;
        for (int w = 0; w < wvp; ++w) base += wc[w];
        const int cnt = wc[0] + wc[1] + wc[2] + wc[3];
        const int act_before = base + pos;
        const int slot = m ? act_before : cnt + (tid - act_before);
        idxB[b * NN + slot] = tid;
        if (tid == 0) cntB[b] = cnt;
    } else {
        // node GEMM: 16 rows per block; B-frags gathered from RAW fp32 we1
        const int r0 = (blk - 328) * 16;
        const int wv = tid >> 6, lane = tid & 63, g = lane >> 4, cl = lane & 15;
        __shared__ __align__(16) unsigned short t1[16 * HD];
        {
            const int row = tid >> 4, k0 = (tid & 15) * 8;
            const float4 a0 = *(const float4*)(h + (size_t)(r0 + row) * HD + k0);
            const float4 a1 = *(const float4*)(h + (size_t)(r0 + row) * HD + k0 + 4);
            uint4 o;
            o.x = pk2(a0.x, a0.y); o.y = pk2(a0.z, a0.w);
            o.z = pk2(a1.x, a1.y); o.w = pk2(a1.z, a1.w);
            *(uint4*)((char*)t1 + swz(row, 2 * k0)) = o;
        }
        __syncthreads();
        const f32x4 zero4 = {0.f, 0.f, 0.f, 0.f};
        f32x4 acc[4] = {zero4, zero4, zero4, zero4};
        #pragma unroll
        for (int ks = 0; ks < 4; ++ks) {
            const short8 a = *(const short8*)((char*)t1 + swz(cl, ks * 64 + g * 16));
            const int k0 = ks * 32 + g * 8;
            #pragma unroll
            for (int nt = 0; nt < 4; ++nt) {
                const int col = wv * 64 + nt * 16 + cl;
                const float* wsrc = (col < HD) ? (we1 + (size_t)k0 * HD + col)
                                               : (we1 + (size_t)(HD + k0) * HD + (col - HD));
                uint4 wp;
                wp.x = pk2(wsrc[0 * HD], wsrc[1 * HD]);
                wp.y = pk2(wsrc[2 * HD], wsrc[3 * HD]);
                wp.z = pk2(wsrc[4 * HD], wsrc[5 * HD]);
                wp.w = pk2(wsrc[6 * HD], wsrc[7 * HD]);
                const short8 bb = *(const short8*)&wp;
                acc[nt] = __builtin_amdgcn_mfma_f32_16x16x32_bf16(a, bb, acc[nt], 0, 0, 0);
            }
        }
        #pragma unroll
        for (int nt = 0; nt < 4; ++nt) {
            const int col = wv * 64 + nt * 16 + cl;
            const float bias = (col < HD) ? be1[col] : 0.f;
            #pragma unroll
            for (int r = 0; r < 4; ++r) {
                const int row = r0 + g * 4 + r;
                const float v = acc[nt][r] + bias;
                if (col < HD) Apre[(size_t)row * HD + col] = v;
                else          Bpre[(size_t)row * HD + (col - HD)] = v;
            }
        }
    }
}

// ---- main: 2 blocks (256 thr / 4 waves each) per node; block owns a j-half ----
// Operand-SWAPPED MFMA, one barrier per chunk, (256,3). [R16 structure]
// Native exp2/rcp silu (5 instrs) replaces library __expf/__fdividef.
__global__ __launch_bounds__(256, 3) void egcl_main(
    const float* __restrict__ x, const float* __restrict__ we1,
    const float* __restrict__ be2, const float* __restrict__ bc1,
    const float* __restrict__ wc2,
    const float* __restrict__ Apre, const float* __restrict__ Bpre,
    const unsigned short* __restrict__ we2pk, const unsigned short* __restrict__ wc1pk,
    const int* __restrict__ idxB, const int* __restrict__ cntB,
    float* __restrict__ aggp, float4* __restrict__ cdws)
{
    const int blk = blockIdx.x;              // 0..4095
    const int b = blk >> 9;
    const int q = blk & 511;
    const int p = q >> 1, hh = q & 1;
    const int tid = threadIdx.x;
    const int wv = tid >> 6, lane = tid & 63, g = lane >> 4, cl = lane & 15;

    const int cnt = cntB[b];
    const int i = idxB[b * NN + p];          // full permutation: [actives | inactives]
    const int rowb = b * NN + i;

    const int nch_t = (cnt + 15) >> 4;
    const int c0 = ((nch_t + 1) >> 1) << 4;  // rows for half 0 (multiple of 16)
    const int jbase = hh ? c0 : 0;
    const int jend  = hh ? cnt : (c0 < cnt ? c0 : cnt);
    const int hcnt  = jend - jbase;

    if (p >= cnt || hcnt <= 0) return;       // partials pre-zeroed by memset

    __shared__ __align__(16) unsigned short m1buf[2][16 * HD]; // 8KB double buffer
    __shared__ __align__(16) unsigned short t2buf[2][16 * HD]; // 8KB double buffer
    __shared__ __align__(16) float4 jx_s[128];                 // {d2, xj0, xj1, xj2} 2KB
    __shared__ int j_s[128];                                   // 512B
    __shared__ __align__(16) float Ai_s[HD], wl_s[HD];         // 1KB
    __shared__ float swsbuf[8][4][16];                         // per-chunk partials 2KB
    __shared__ float cdp[4][3];

    const float xi0 = x[rowb * 3 + 0];
    const float xi1 = x[rowb * 3 + 1];
    const float xi2 = x[rowb * 3 + 2];
    const int nch = (hcnt + 15) >> 4;        // <= 8

    // block-start staging: local j list, xj, d2; Ai; wlast
    if (tid < nch * 16) {
        const int j = (tid < hcnt) ? idxB[b * NN + jbase + tid] : i;
        const float* xj = x + (b * NN + j) * 3;
        const float x0 = xj[0], x1 = xj[1], x2 = xj[2];
        const float dx = xi0 - x0, dy = xi1 - x1, dz = xi2 - x2;
        float4 v; v.x = dx * dx + dy * dy + dz * dz + 1e-8f;
        v.y = x0; v.z = x1; v.w = x2;
        jx_s[tid] = v; j_s[tid] = j;
    }
    if (tid < HD) Ai_s[tid] = Apre[(size_t)rowb * HD + tid];
    else if (tid < 2 * HD) wl_s[tid - HD] = we1[2 * HD * HD + (tid - HD)];

    // per-wave weight fragments: wave owns output cols [wv*32, wv*32+32)
    short8 bw2[4][2], bwc[4][2];
    #pragma unroll
    for (int ks = 0; ks < 4; ++ks) {
        #pragma unroll
        for (int nt = 0; nt < 2; ++nt) {
            const int off = ((ks * 4 + g) * HD + wv * 32 + nt * 16 + cl) * 8;
            bw2[ks][nt] = *(const short8*)(we2pk + off);
            bwc[ks][nt] = *(const short8*)(wc1pk + off);
        }
    }
    // per-(nt,ri) bias/scale scalars at n = wv*32 + nt*16 + g*4 + ri
    float be2v[2][4], bc1v[2][4], wc2v[2][4];
    #pragma unroll
    for (int nt = 0; nt < 2; ++nt) {
        #pragma unroll
        for (int ri = 0; ri < 4; ++ri) {
            const int n = wv * 32 + nt * 16 + g * 4 + ri;
            be2v[nt][ri] = be2[n]; bc1v[nt][ri] = bc1[n]; wc2v[nt][ri] = wc2[n];
        }
    }

    float agg2[2][4] = {{0.f, 0.f, 0.f, 0.f}, {0.f, 0.f, 0.f, 0.f}};
    const f32x4 zero4 = {0.f, 0.f, 0.f, 0.f};

    // phase-A lane mapping: 256 lanes cover [16 rows][128 K], 8 K-elems each
    const int arow = tid >> 4;           // 0..15
    const int ak0  = (tid & 15) * 8;     // 0,8,...,120
    float4 sb0, sb1;                     // prefetched Bpre[j, ak0..ak0+8)

    // issue Bpre loads for chunk C (held in regs across GEMM1/epi1)
    #define ISSUE(C) do { \
        const float* bp_ = Bpre + (size_t)(b * NN + j_s[(C) * 16 + arow]) * HD + ak0; \
        sb0 = *(const float4*)(bp_); \
        sb1 = *(const float4*)(bp_ + 4); \
    } while (0)

    // phase A for chunk C -> dst buffer (consumes sb0/sb1)
    #define APHASE(C, DST) do { \
        const float d2_ = jx_s[(C) * 16 + arow].x; \
        const float4 a0 = *(const float4*)(Ai_s + ak0); \
        const float4 a1 = *(const float4*)(Ai_s + ak0 + 4); \
        const float4 w0 = *(const float4*)(wl_s + ak0); \
        const float4 w1 = *(const float4*)(wl_s + ak0 + 4); \
        uint4 o; \
        o.x = pk2(fsilu(a0.x + sb0.x + d2_ * w0.x), fsilu(a0.y + sb0.y + d2_ * w0.y)); \
        o.y = pk2(fsilu(a0.z + sb0.z + d2_ * w0.z), fsilu(a0.w + sb0.w + d2_ * w0.w)); \
        o.z = pk2(fsilu(a1.x + sb1.x + d2_ * w1.x), fsilu(a1.y + sb1.y + d2_ * w1.y)); \
        o.w = pk2(fsilu(a1.z + sb1.z + d2_ * w1.z), fsilu(a1.w + sb1.w + d2_ * w1.w)); \
        *(uint4*)((char*)(DST) + swz(arow, 2 * ak0)) = o; \
    } while (0)

    unsigned short* m1cur = m1buf[0];
    unsigned short* m1nxt = m1buf[1];
    unsigned short* t2cur = t2buf[0];
    unsigned short* t2nxt = t2buf[1];

    __syncthreads();                 // staging LDS visible
    ISSUE(0);
    APHASE(0, m1cur);
    __syncthreads();                 // m1cur visible

    for (int c = 0; c < nch; ++c) {
        // issue next chunk's loads early: GEMM1+epi1 cover the L2 latency
        if (c + 1 < nch) ISSUE(c + 1);
        // ---- GEMM1 (swapped): acc[nt] = out1^T tiles; lane col = j-row ----
        f32x4 acc[2] = {zero4, zero4};
        #pragma unroll
        for (int ks = 0; ks < 4; ++ks) {
            const short8 mf = *(const short8*)((const char*)m1cur + swz(cl, 2 * (ks * 32 + g * 8)));
            acc[0] = __builtin_amdgcn_mfma_f32_16x16x32_bf16(bw2[ks][0], mf, acc[0], 0, 0, 0);
            acc[1] = __builtin_amdgcn_mfma_f32_16x16x32_bf16(bw2[ks][1], mf, acc[1], 0, 0, 0);
        }
        // ---- epilogue 1: v = silu(+be2)*mask(row=cl); agg; 2x b64 store ----
        {
            const float mp = (c * 16 + cl < hcnt) ? 1.f : 0.f;
            #pragma unroll
            for (int nt = 0; nt < 2; ++nt) {
                const float v0 = fsilu(acc[nt][0] + be2v[nt][0]) * mp;
                const float v1 = fsilu(acc[nt][1] + be2v[nt][1]) * mp;
                const float v2 = fsilu(acc[nt][2] + be2v[nt][2]) * mp;
                const float v3 = fsilu(acc[nt][3] + be2v[nt][3]) * mp;
                agg2[nt][0] += v0; agg2[nt][1] += v1;
                agg2[nt][2] += v2; agg2[nt][3] += v3;
                uint2 o; o.x = pk2(v0, v1); o.y = pk2(v2, v3);
                *(uint2*)((char*)t2cur + swz(cl, 2 * (wv * 32 + nt * 16 + g * 4))) = o;
            }
        }
        // ---- next chunk's phase A into the other m1 buffer ----
        if (c + 1 < nch) APHASE(c + 1, m1nxt);
        __syncthreads();             // the ONLY barrier per chunk
        // ---- GEMM2 (swapped): acc2[nt] = out2^T tiles ----
        f32x4 acc2[2] = {zero4, zero4};
        #pragma unroll
        for (int ks = 0; ks < 4; ++ks) {
            const short8 tf = *(const short8*)((const char*)t2cur + swz(cl, 2 * (ks * 32 + g * 8)));
            acc2[0] = __builtin_amdgcn_mfma_f32_16x16x32_bf16(bwc[ks][0], tf, acc2[0], 0, 0, 0);
            acc2[1] = __builtin_amdgcn_mfma_f32_16x16x32_bf16(bwc[ks][1], tf, acc2[1], 0, 0, 0);
        }
        // ---- epilogue 2: in-lane col reduction; 2 shfl across g; -> swsbuf[c] ----
        {
            float sr = fsilu(acc2[0][0] + bc1v[0][0]) * wc2v[0][0]
                     + fsilu(acc2[0][1] + bc1v[0][1]) * wc2v[0][1]
                     + fsilu(acc2[0][2] + bc1v[0][2]) * wc2v[0][2]
                     + fsilu(acc2[0][3] + bc1v[0][3]) * wc2v[0][3]
                     + fsilu(acc2[1][0] + bc1v[1][0]) * wc2v[1][0]
                     + fsilu(acc2[1][1] + bc1v[1][1]) * wc2v[1][1]
                     + fsilu(acc2[1][2] + bc1v[1][2]) * wc2v[1][2]
                     + fsilu(acc2[1][3] + bc1v[1][3]) * wc2v[1][3];
            sr += __shfl_xor(sr, 16);
            sr += __shfl_xor(sr, 32);
            if (lane < 16) swsbuf[c][wv][cl] = sr;
        }
        // swap buffers
        unsigned short* tmp = m1cur; m1cur = m1nxt; m1nxt = tmp;
        tmp = t2cur; t2cur = t2nxt; t2nxt = tmp;
    }
    #undef ISSUE
    #undef APHASE
    __syncthreads();                 // all swsbuf visible

    // ---- deferred coord finalize: thread jl handles one j ----
    float cdx = 0.f, cdy = 0.f, cdz = 0.f;
    if (tid < hcnt) {
        const int ch = tid >> 4, row = tid & 15;
        const float s = swsbuf[ch][0][row] + swsbuf[ch][1][row]
                      + swsbuf[ch][2][row] + swsbuf[ch][3][row];
        const float w = ftanh(s) * 0.1f;
        const float4 jx = jx_s[tid];
        cdx = (xi0 - jx.y) * w;
        cdy = (xi1 - jx.z) * w;
        cdz = (xi2 - jx.w) * w;
    }
    #pragma unroll
    for (int m = 1; m <= 32; m <<= 1) {
        cdx += __shfl_xor(cdx, m);
        cdy += __shfl_xor(cdy, m);
        cdz += __shfl_xor(cdz, m);
    }
    if (lane == 0) { cdp[wv][0] = cdx; cdp[wv][1] = cdy; cdp[wv][2] = cdz; }

    // agg: reduce each (nt,ri) over j-rows (cl lanes); lane cl==0 per g writes
    const size_t aggbase = ((size_t)hh * NB + rowb) * HD;
    #pragma unroll
    for (int nt = 0; nt < 2; ++nt) {
        #pragma unroll
        for (int ri = 0; ri < 4; ++ri) {
            float a = agg2[nt][ri];
            a += __shfl_xor(a, 1); a += __shfl_xor(a, 2);
            a += __shfl_xor(a, 4); a += __shfl_xor(a, 8);
            if (cl == 0) aggp[aggbase + wv * 32 + nt * 16 + g * 4 + ri] = a;
        }
    }
    __syncthreads();
    if (tid == 0) {
        cdws[hh * NB + rowb] = make_float4(cdp[0][0] + cdp[1][0] + cdp[2][0] + cdp[3][0],
                                           cdp[0][1] + cdp[1][1] + cdp[2][1] + cdp[3][1],
                                           cdp[0][2] + cdp[1][2] + cdp[2][2] + cdp[3][2], 0.f);
    }
}

// ---- node MLP + LayerNorm + coord finalize: 16 rows per block ----
__global__ __launch_bounds__(256) void node_mlp(
    const float* __restrict__ h, const float* __restrict__ x,
    const float* __restrict__ aggp, const float4* __restrict__ cdws,
    const unsigned short* __restrict__ wn1pk, const unsigned short* __restrict__ wn2pk,
    const float* __restrict__ bn1, const float* __restrict__ bn2,
    const float* __restrict__ gamma, const float* __restrict__ beta,
    float* __restrict__ hout, float* __restrict__ xout)
{
    const int r0 = blockIdx.x * 16;
    const int tid = threadIdx.x;
    const int wv = tid >> 6, lane = tid & 63, g = lane >> 4, cl = lane & 15;
    __shared__ __align__(16) unsigned short t1[16 * 256];
    __shared__ __align__(16) unsigned short t2[16 * HD];
    __shared__ float rs1[4][16], rs2[4][16];
    __shared__ float bn1_s[HD], bn2_s[HD], gam_s[HD], bet_s[HD];
    if (tid < HD) {
        bn1_s[tid] = bn1[tid]; bn2_s[tid] = bn2[tid];
        gam_s[tid] = gamma[tid]; bet_s[tid] = beta[tid];
    }
    // coord finalize (independent of the MLP)
    if (tid >= 128 && tid < 144) {
        const int row = r0 + (tid - 128);
        const float4 c0 = cdws[row], c1 = cdws[NB + row];
        xout[row * 3 + 0] = x[row * 3 + 0] + (c0.x + c1.x) * (1.f / 256.f);
        xout[row * 3 + 1] = x[row * 3 + 1] + (c0.y + c1.y) * (1.f / 256.f);
        xout[row * 3 + 2] = x[row * 3 + 2] + (c0.z + c1.z) * (1.f / 256.f);
    }
    // stage A tile: [16 rows][256 k] = [h | agg0+agg1] bf16, swizzled
    {
        const int row = tid >> 4, k0 = (tid & 15) * 16;
        const size_t off = (size_t)(r0 + row) * HD;
        char* dst = (char*)t1;
        if (k0 < HD) {
            #pragma unroll
            for (int u = 0; u < 16; u += 8) {
                const float4 a0 = *(const float4*)(h + off + k0 + u);
                const float4 a1 = *(const float4*)(h + off + k0 + u + 4);
                uint4 o;
                o.x = pk2(a0.x, a0.y); o.y = pk2(a0.z, a0.w);
                o.z = pk2(a1.x, a1.y); o.w = pk2(a1.z, a1.w);
                *(uint4*)(dst + swz512(row, 2 * (k0 + u))) = o;
            }
        } else {
            const int kk = k0 - HD;
            #pragma unroll
            for (int u = 0; u < 16; u += 8) {
                const float4 a0 = *(const float4*)(aggp + off + kk + u);
                const float4 a1 = *(const float4*)(aggp + off + kk + u + 4);
                const float4 b0 = *(const float4*)(aggp + (size_t)NB * HD + off + kk + u);
                const float4 b1 = *(const float4*)(aggp + (size_t)NB * HD + off + kk + u + 4);
                uint4 o;
                o.x = pk2(a0.x + b0.x, a0.y + b0.y); o.y = pk2(a0.z + b0.z, a0.w + b0.w);
                o.z = pk2(a1.x + b1.x, a1.y + b1.y); o.w = pk2(a1.z + b1.z, a1.w + b1.w);
                *(uint4*)(dst + swz512(row, 2 * (k0 + u))) = o;
            }
        }
    }
    __syncthreads();
    const f32x4 zero4 = {0.f, 0.f, 0.f, 0.f};
    f32x4 acc[2] = {zero4, zero4};
    #pragma unroll
    for (int ks = 0; ks < 8; ++ks) {
        const short8 a = *(const short8*)((char*)t1 + swz512(cl, ks * 64 + g * 16));
        #pragma unroll
        for (int nt = 0; nt < 2; ++nt) {
            const int col = wv * 32 + nt * 16 + cl;
            const short8 bb = *(const short8*)(wn1pk + ((ks * 4 + g) * HD + col) * 8);
            acc[nt] = __builtin_amdgcn_mfma_f32_16x16x32_bf16(a, bb, acc[nt], 0, 0, 0);
        }
    }
    #pragma unroll
    for (int nt = 0; nt < 2; ++nt) {
        const int col = wv * 32 + nt * 16 + cl;
        const float bias = bn1_s[col];
        #pragma unroll
        for (int r = 0; r < 4; ++r) {
            const int row = g * 4 + r;
            *(unsigned short*)((char*)t2 + swz(row, 2 * col)) = us(fsilu(acc[nt][r] + bias));
        }
    }
    __syncthreads();
    f32x4 acc2[2] = {zero4, zero4};
    #pragma unroll
    for (int ks = 0; ks < 4; ++ks) {
        const short8 a = *(const short8*)((char*)t2 + swz(cl, ks * 64 + g * 16));
        #pragma unroll
        for (int nt = 0; nt < 2; ++nt) {
            const int col = wv * 32 + nt * 16 + cl;
            const short8 bb = *(const short8*)(wn2pk + ((ks * 4 + g) * HD + col) * 8);
            acc2[nt] = __builtin_amdgcn_mfma_f32_16x16x32_bf16(a, bb, acc2[nt], 0, 0, 0);
        }
    }
    float h2[2][4];
    #pragma unroll
    for (int nt = 0; nt < 2; ++nt) {
        const int col = wv * 32 + nt * 16 + cl;
        #pragma unroll
        for (int r = 0; r < 4; ++r) {
            const int row = g * 4 + r;
            h2[nt][r] = acc2[nt][r] + bn2_s[col] + h[(size_t)(r0 + row) * HD + col];
        }
    }
    #pragma unroll
    for (int r = 0; r < 4; ++r) {
        float pp = h2[0][r] + h2[1][r];
        pp += __shfl_xor(pp, 1); pp += __shfl_xor(pp, 2);
        pp += __shfl_xor(pp, 4); pp += __shfl_xor(pp, 8);
        if (cl == 0) rs1[wv][g * 4 + r] = pp;
    }
    __syncthreads();
    float mean[4];
    #pragma unroll
    for (int r = 0; r < 4; ++r) {
        const int row = g * 4 + r;
        mean[r] = (rs1[0][row] + rs1[1][row] + rs1[2][row] + rs1[3][row]) * (1.f / HD);
    }
    #pragma unroll
    for (int r = 0; r < 4; ++r) {
        const float d0 = h2[0][r] - mean[r], d1 = h2[1][r] - mean[r];
        float qq = d0 * d0 + d1 * d1;
        qq += __shfl_xor(qq, 1); qq += __shfl_xor(qq, 2);
        qq += __shfl_xor(qq, 4); qq += __shfl_xor(qq, 8);
        if (cl == 0) rs2[wv][g * 4 + r] = qq;
    }
    __syncthreads();
    #pragma unroll
    for (int r = 0; r < 4; ++r) {
        const int row = g * 4 + r;
        const float var = (rs2[0][row] + rs2[1][row] + rs2[2][row] + rs2[3][row]) * (1.f / HD);
        const float rsq = rsqrtf(var + 1e-5f);
        #pragma unroll
        for (int nt = 0; nt < 2; ++nt) {
            const int col = wv * 32 + nt * 16 + cl;
            hout[(size_t)(r0 + row) * HD + col] = (h2[nt][r] - mean[r]) * rsq * gam_s[col] + bet_s[col];
        }
    }
}

extern "C" void kernel_launch(void* const* d_in, const int* in_sizes, int n_in,
                              void* d_out, int out_size, void* d_ws, size_t ws_size,
                              hipStream_t stream)
{
    (void)in_sizes; (void)n_in; (void)out_size; (void)ws_size;
    const float* h     = (const float*)d_in[0];
    const float* x     = (const float*)d_in[1];
    const int*   mask  = (const int*)d_in[2];
    const float* we1   = (const float*)d_in[3];
    const float* be1   = (const float*)d_in[4];
    const float* we2   = (const float*)d_in[5];
    const float* be2   = (const float*)d_in[6];
    const float* wn1   = (const float*)d_in[7];
    const float* bn1   = (const float*)d_in[8];
    const float* wn2   = (const float*)d_in[9];
    const float* bn2   = (const float*)d_in[10];
    const float* wc1   = (const float*)d_in[11];
    const float* bc1   = (const float*)d_in[12];
    const float* wc2   = (const float*)d_in[13];
    const float* gamma = (const float*)d_in[14];
    const float* beta  = (const float*)d_in[15];

    float* out  = (float*)d_out;
    float* hout = out;
    float* xout = out + NB * HD;

    float* Apre  = (float*)d_ws;                       // 2048*128
    float* Bpre  = Apre + NB * HD;                     // 2048*128
    float* aggp  = Bpre + NB * HD;                     // 2*2048*128
    float4* cdws = (float4*)(aggp + 2 * NB * HD);      // 2*2048 float4 (contiguous after aggp)
    unsigned short* we2pk = (unsigned short*)(cdws + 2 * NB);
    unsigned short* wc1pk = we2pk + 128 * 128;
    unsigned short* wn1pk = wc1pk + 128 * 128;
    unsigned short* wn2pk = wn1pk + 256 * 128;
    int* idxB = (int*)(wn2pk + 128 * 128);
    int* cntB = idxB + 8 * NN;

    // zero the partial buffers (aggp + cdws contiguous): inactive tasks never write
    hipMemsetAsync(aggp, 0, (size_t)(2 * NB * HD) * sizeof(float) + (size_t)(2 * NB) * sizeof(float4), stream);
    prep_fused<<<456, 256, 0, stream>>>(we2, wc1, wn1, wn2, we1, mask, h, be1,
                                        we2pk, wc1pk, wn1pk, wn2pk, idxB, cntB,
                                        Apre, Bpre);
    egcl_main<<<NB * 2, 256, 0, stream>>>(x, we1, be2, bc1, wc2,
                                          Apre, Bpre, we2pk, wc1pk, idxB, cntB,
                                          aggp, cdws);
    node_mlp<<<128, 256, 0, stream>>>(h, x, aggp, cdws, wn1pk, wn2pk,
                                      bn1, bn2, gamma, beta, hout, xout);
}